// Round 6
// baseline (503.152 us; speedup 1.0000x reference)
//
#include <hip/hip_runtime.h>
#include <math.h>

#define N_NODES 10000
#define E_EDGES 320000
#define IN_DIM 128
#define EMB 128
#define HID 64
#define NEG_SLOPE 0.2f

#define DG_BLOCKS 625          // dense_gat: 625 * 16 rows = 10000
#define CNT_BLOCKS 665         // count rider blocks
#define TOTAL_EDGES (E_EDGES + N_NODES)

typedef __attribute__((ext_vector_type(8))) short short8;     // 8 bf16 (4 VGPR)
typedef __attribute__((ext_vector_type(4))) short short4_t;   // 4 bf16
typedef __attribute__((ext_vector_type(4))) float floatx4;    // 4 fp32
typedef __attribute__((ext_vector_type(8))) float floatx8;    // 8 fp32
typedef __attribute__((ext_vector_type(2))) int   intx2;

// fp32 -> bf16 bits, round-to-nearest-even
__device__ __forceinline__ short f2bf(float f) {
    unsigned u = __float_as_uint(f);
    unsigned r = u + 0x7fffu + ((u >> 16) & 1u);
    return (short)(r >> 16);
}

__device__ __forceinline__ float sigmoidf_fast(float v) {
    return __builtin_amdgcn_rcpf(1.f + __expf(-v));
}

// ---------------------------------------------------------------------------
// Kernel A+count: blocks 0..624 run the dense+GAT GEMMs (R2 structure);
// blocks 625..1289 count edge in-degrees (independent outputs, no sync
// needed -> count hides completely under the GEMM work).
// ---------------------------------------------------------------------------
__global__ __launch_bounds__(256) void dense_gat_count_kernel(
    const float* __restrict__ x, const float* __restrict__ dw,
    const float* __restrict__ db, const float* __restrict__ gw,
    const float* __restrict__ asv, const float* __restrict__ adv,
    const int* __restrict__ ei,
    float* __restrict__ z, float* __restrict__ a_src, float* __restrict__ a_dst,
    int* __restrict__ cnt)
{
    __shared__ float smem[8192];         // 32 KB
    const int t = threadIdx.x;
    const int b = blockIdx.x;

    if (b >= DG_BLOCKS) {                // ---- count rider ----
        const int nth = CNT_BLOCKS * 256;
        for (int e = (b - DG_BLOCKS) * 256 + t; e < TOTAL_EDGES; e += nth) {
            int s, d;
            if (e < E_EDGES) { s = ei[e]; d = ei[E_EDGES + e]; }
            else             { s = d = e - E_EDGES; }
            if ((unsigned)s >= N_NODES || (unsigned)d >= N_NODES) continue;
            atomicAdd(&cnt[d], 1);
        }
        return;
    }

    float* const xs  = smem;             // [16][128]
    float* const hs  = smem + 2048;      // [16][128]
    float* const wsm = smem + 4096;      // [32*128] / [64*64]
    const int row0 = b * 16;             // 10000 % 16 == 0

    #pragma unroll
    for (int r = 0; r < 2; ++r) {
        const int idx = t + r * 256;           // 0..511 float4 slots
        const int row = idx >> 5, c4 = idx & 31;
        *(floatx4*)&xs[row * 128 + c4 * 4] =
            *(const floatx4*)&x[(row0 + row) * IN_DIM + c4 * 4];
    }

    // GEMM1: col = t&127, rows (t>>7)*8 .. +8
    const int col = t & 127, rb = (t >> 7) * 8;
    float acc[8];
    {
        const float bias = db[col];
        #pragma unroll
        for (int r = 0; r < 8; ++r) acc[r] = bias;
    }
    for (int ch = 0; ch < 4; ++ch) {
        __syncthreads();                       // xs ready (ch=0) / wsm reads done
        #pragma unroll
        for (int r = 0; r < 4; ++r) {          // stage dw[ch*32..+32][0..128]
            const int idx = t + r * 256;
            const int row = idx >> 5, c4 = idx & 31;
            *(floatx4*)&wsm[row * 128 + c4 * 4] =
                *(const floatx4*)&dw[(ch * 32 + row) * EMB + c4 * 4];
        }
        __syncthreads();
        #pragma unroll
        for (int jg = 0; jg < 8; ++jg) {
            const int jb = jg * 4;
            floatx4 xr[8];
            #pragma unroll
            for (int r = 0; r < 8; ++r)
                xr[r] = *(const floatx4*)&xs[(rb + r) * 128 + ch * 32 + jb];
            float wv[4];
            #pragma unroll
            for (int k = 0; k < 4; ++k) wv[k] = wsm[(jb + k) * 128 + col];
            #pragma unroll
            for (int k = 0; k < 4; ++k)
                #pragma unroll
                for (int r = 0; r < 8; ++r) acc[r] = fmaf(xr[r][k], wv[k], acc[r]);
        }
    }
    #pragma unroll
    for (int r = 0; r < 8; ++r) hs[(rb + r) * 128 + col] = fmaxf(acc[r], 0.f);

    // GEMM2: col2 = t&63, rows (t>>6)*4 .. +4
    const int col2 = t & 63, rb2 = (t >> 6) * 4;
    float acc2[4] = {0.f, 0.f, 0.f, 0.f};
    for (int ch = 0; ch < 2; ++ch) {
        __syncthreads();                       // hs ready / wsm reads done
        #pragma unroll
        for (int r = 0; r < 4; ++r) {          // stage gw[ch*64..+64][0..64]
            const int idx = t + r * 256;
            const int row = idx >> 4, c4 = idx & 15;
            *(floatx4*)&wsm[row * 64 + c4 * 4] =
                *(const floatx4*)&gw[(ch * 64 + row) * HID + c4 * 4];
        }
        __syncthreads();
        #pragma unroll
        for (int kg = 0; kg < 16; ++kg) {
            const int kb = kg * 4;
            floatx4 hr[4];
            #pragma unroll
            for (int r = 0; r < 4; ++r)
                hr[r] = *(const floatx4*)&hs[(rb2 + r) * 128 + ch * 64 + kb];
            float gv[4];
            #pragma unroll
            for (int k = 0; k < 4; ++k) gv[k] = wsm[(kb + k) * 64 + col2];
            #pragma unroll
            for (int k = 0; k < 4; ++k)
                #pragma unroll
                for (int r = 0; r < 4; ++r) acc2[r] = fmaf(hr[r][k], gv[k], acc2[r]);
        }
    }

    // store z + fused attention dot products (wave holds full row of 64 cols)
    const float as_c = asv[col2], ad_c = adv[col2];
    #pragma unroll
    for (int r = 0; r < 4; ++r) {
        z[(row0 + rb2 + r) * HID + col2] = acc2[r];
        float ps = acc2[r] * as_c;
        float pd = acc2[r] * ad_c;
        #pragma unroll
        for (int off = 32; off > 0; off >>= 1) {
            ps += __shfl_down(ps, off, 64);
            pd += __shfl_down(pd, off, 64);
        }
        if ((t & 63) == 0) {
            a_src[row0 + rb2 + r] = ps;
            a_dst[row0 + rb2 + r] = pd;
        }
    }
}

// ---------------------------------------------------------------------------
// scan: single block, 1024 threads, 10 items each (10240 >= 10000).
// ---------------------------------------------------------------------------
__global__ __launch_bounds__(1024) void scan_kernel(
    const int* __restrict__ cnt, int* __restrict__ offs, int* __restrict__ cursor)
{
    __shared__ int part[1024];
    const int t = threadIdx.x;
    const int base = t * 10;
    int vals[10];
    int local = 0;
    #pragma unroll
    for (int i = 0; i < 10; ++i) {
        const int idx = base + i;
        const int c = (idx < N_NODES) ? cnt[idx] : 0;
        vals[i] = c;
        local += c;
    }
    part[t] = local;
    __syncthreads();
    for (int off = 1; off < 1024; off <<= 1) {  // Hillis-Steele inclusive
        const int v = (t >= off) ? part[t - off] : 0;
        __syncthreads();
        part[t] += v;
        __syncthreads();
    }
    int running = (t == 0) ? 0 : part[t - 1];   // exclusive base
    #pragma unroll
    for (int i = 0; i < 10; ++i) {
        const int idx = base + i;
        if (idx < N_NODES) { offs[idx] = running; cursor[idx] = running; }
        running += vals[i];
    }
    if (t == 1023) offs[N_NODES] = running;
}

// ---------------------------------------------------------------------------
// scatter: ei loads nontemporal (last use -> keep L2 for z / write-merging).
// se stores stay CACHED: 8B scattered stores rely on L2 write-merging.
// ---------------------------------------------------------------------------
__global__ __launch_bounds__(256) void scatter_kernel(
    const int* __restrict__ ei, const float* __restrict__ a_src,
    const float* __restrict__ a_dst, int* __restrict__ cursor,
    intx2* __restrict__ se)
{
    const int e = blockIdx.x * blockDim.x + threadIdx.x;
    if (e >= TOTAL_EDGES) return;
    int s, d;
    if (e < E_EDGES) {
        s = __builtin_nontemporal_load(&ei[e]);
        d = __builtin_nontemporal_load(&ei[E_EDGES + e]);
    } else {
        s = d = e - E_EDGES;
    }
    if ((unsigned)s >= N_NODES || (unsigned)d >= N_NODES) return;
    float v = a_src[s] + a_dst[d];
    v = (v > 0.f) ? v : NEG_SLOPE * v;
    const float w = __expf(v);          // max-shift skipped: |v| small, fp32 safe
    const int pos = atomicAdd(&cursor[d], 1);
    intx2 p;
    p[0] = s;
    p[1] = __float_as_int(w);
    se[pos] = p;                        // one 8B record (cached store)
}

// ---------------------------------------------------------------------------
// aggregate v3: one wave per node; 8 edge subgroups of 8 lanes x float8 so
// EIGHT dependent se->z chains are in flight (mean degree 33 -> ~4 iters).
// se loads nontemporal (streaming; don't evict the 2.56MB z table from L2);
// z loads cached (L2-resident per XCD); emb store nontemporal.
// ---------------------------------------------------------------------------
__global__ __launch_bounds__(256) void aggregate_kernel(
    const int* __restrict__ offs, const intx2* __restrict__ se,
    const float* __restrict__ z, const float* __restrict__ gb,
    float* __restrict__ emb)
{
    const int wid  = (blockIdx.x * blockDim.x + threadIdx.x) >> 6;
    const int lane = threadIdx.x & 63;
    if (wid >= N_NODES) return;
    const int g  = lane >> 3;            // edge subgroup 0..7
    const int c8 = (lane & 7) * 8;       // feature slot (8 floats = 32B)
    const int beg = offs[wid], end = offs[wid + 1];
    floatx8 acc = {0.f, 0.f, 0.f, 0.f, 0.f, 0.f, 0.f, 0.f};
    float sw = 0.f;
    for (int i = beg + g; i < end; i += 8) {
        const intx2 p = __builtin_nontemporal_load(&se[i]);   // broadcast in group
        const floatx8 zv = *(const floatx8*)&z[p[0] * HID + c8];
        const float w = __int_as_float(p[1]);
        acc += zv * w;
        sw  += w;
    }
    #pragma unroll
    for (int off = 8; off <= 32; off <<= 1) {
        #pragma unroll
        for (int k = 0; k < 8; ++k) acc[k] += __shfl_xor(acc[k], off, 64);
        sw += __shfl_xor(sw, off, 64);
    }
    if (g == 0) {                        // lanes 0..7 cover the 64-col row
        const floatx8 gv = *(const floatx8*)&gb[c8];
        floatx8 r;
        #pragma unroll
        for (int k = 0; k < 8; ++k) r[k] = acc[k] / sw + gv[k];
        __builtin_nontemporal_store(r, (floatx8*)&emb[wid * HID + c8]);
    }
}

// ---------------------------------------------------------------------------
// Kernel D: sim = sigmoid(emb @ emb^T). FULL 79x79 grid, normal-orientation
// stores only. 256 thr, 4 waves; wave w owns row-fragments {w, w+4}
// (INTERLEAVED) so both epilogue halves keep every wave busy. Epilogue:
// sigmoid half-tile into a [64][133] f32 scratch aliased over the staging
// buffers, then 512B-contiguous NT float4 runs. LDS = 36864 B -> 4 blocks/CU.
// ---------------------------------------------------------------------------
#define SROW 72
#define SCR 133
__global__ __launch_bounds__(256, 4) void sim_kernel(
    const float* __restrict__ emb, float* __restrict__ sim)
{
    __shared__ float smem[9216];                   // 36864 B
    short* const As = (short*)smem;                // [128*72] bf16
    short* const Bs = (short*)smem + 128 * SROW;   // [128*72] bf16
    float* const scr = smem;                       // [64][133] f32 (aliased)
    const int t    = threadIdx.x;
    const int lane = t & 63;
    const int wave = t >> 6;                 // 0..3
    const int l15  = lane & 15;
    const int quad = lane >> 4;              // 0..3

    const int bi = blockIdx.y;               // row tile
    const int bj = blockIdx.x;               // col tile

    // ---- stage both row-tiles as bf16 into LDS (8 rounds x 256 thr) ----
    #pragma unroll
    for (int round = 0; round < 8; ++round) {
        const int idx = t + round * 256;     // 0..2047
        const int row = idx >> 4, c4 = idx & 15;
        int gr = bi * 128 + row; if (gr > N_NODES - 1) gr = N_NODES - 1;
        int gc = bj * 128 + row; if (gc > N_NODES - 1) gc = N_NODES - 1;
        const floatx4 a = *(const floatx4*)&emb[gr * HID + c4 * 4];
        const floatx4 b = *(const floatx4*)&emb[gc * HID + c4 * 4];
        short4_t sa, sb;
        #pragma unroll
        for (int j = 0; j < 4; ++j) { sa[j] = f2bf(a[j]); sb[j] = f2bf(b[j]); }
        *(short4_t*)&As[row * SROW + c4 * 4] = sa;
        *(short4_t*)&Bs[row * SROW + c4 * 4] = sb;
    }
    __syncthreads();

    // ---- fragments + MFMA: wave owns rows (ti*4+wave)*16 .. +16, all cols --
    short8 afrag[2][2];
    #pragma unroll
    for (int ti = 0; ti < 2; ++ti)
        #pragma unroll
        for (int ks = 0; ks < 2; ++ks)
            afrag[ti][ks] = *(const short8*)&As[((ti * 4 + wave) * 16 + l15) * SROW +
                                                ks * 32 + quad * 8];

    floatx4 acc[2][8];
    const floatx4 zero = {0.f, 0.f, 0.f, 0.f};
    #pragma unroll
    for (int ti = 0; ti < 2; ++ti)
        #pragma unroll
        for (int tj = 0; tj < 8; ++tj) acc[ti][tj] = zero;

    #pragma unroll
    for (int tj = 0; tj < 8; ++tj) {
        const short8 bf0 = *(const short8*)&Bs[(tj * 16 + l15) * SROW + quad * 8];
        const short8 bf1 = *(const short8*)&Bs[(tj * 16 + l15) * SROW + 32 + quad * 8];
        #pragma unroll
        for (int ti = 0; ti < 2; ++ti) {
            acc[ti][tj] = __builtin_amdgcn_mfma_f32_16x16x32_bf16(
                afrag[ti][0], bf0, acc[ti][tj], 0, 0, 0);
            acc[ti][tj] = __builtin_amdgcn_mfma_f32_16x16x32_bf16(
                afrag[ti][1], bf1, acc[ti][tj], 0, 0, 0);
        }
    }
    __syncthreads();   // all LDS tile reads done before scratch reuse

    // ---- epilogue: two 64-row halves; EVERY wave active in each phase ----
    #pragma unroll
    for (int h = 0; h < 2; ++h) {
        // wave's fragment ti=h covers rows-in-half wave*16 .. +16
        // C/D layout: row = quad*4+reg (within 16), col = l15
        #pragma unroll
        for (int reg = 0; reg < 4; ++reg)
            #pragma unroll
            for (int tj = 0; tj < 8; ++tj)
                scr[(wave * 16 + quad * 4 + reg) * SCR + tj * 16 + l15] =
                    sigmoidf_fast(acc[h][tj][reg]);
        __syncthreads();

        // 64 rows x 128 cols, 512B contiguous NT float4 runs
        #pragma unroll
        for (int round = 0; round < 8; ++round) {
            const int idx = t + round * 256;         // 0..2047
            const int rr = idx >> 5, cq = idx & 31;
            const int grow = bi * 128 + (h * 4 + (rr >> 4)) * 16 + (rr & 15);
            const int gcol = bj * 128 + cq * 4;
            if (grow < N_NODES && gcol < N_NODES) {
                const floatx4 v4 = *(const floatx4*)&scr[rr * SCR + cq * 4];
                __builtin_nontemporal_store(
                    v4, (floatx4*)&sim[(unsigned)grow * N_NODES + gcol]);
            }
        }
        __syncthreads();    // scratch reads done before next half overwrites
    }
}

// ---------------------------------------------------------------------------
extern "C" void kernel_launch(void* const* d_in, const int* in_sizes, int n_in,
                              void* d_out, int out_size, void* d_ws, size_t ws_size,
                              hipStream_t stream)
{
    const float* x   = (const float*)d_in[0];
    const int*   ei  = (const int*)d_in[1];   // edge_index int32 [2,E]
    const float* dw  = (const float*)d_in[2];
    const float* db  = (const float*)d_in[3];
    const float* gw  = (const float*)d_in[4];
    const float* asv = (const float*)d_in[5];
    const float* adv = (const float*)d_in[6];
    const float* gb  = (const float*)d_in[7];

    float* out = (float*)d_out;
    float* sim = out;                                   // [N*N]
    float* emb = out + (size_t)N_NODES * N_NODES;       // [N*HID]

    // Scratch (all dead before sim_kernel):
    // z 640000 | a_src 10000 | a_dst 10000 | cnt 10000 | offs 10001 |
    // cursor 10000 | pad 1 | se (int2) 330000*2  => 1,350,002 * 4B ~= 5.4 MB
    const size_t need = 1350002u * sizeof(float);
    float* ws = (ws_size >= need) ? (float*)d_ws : out;  // fallback: carve sim
    float* z      = ws;
    float* a_src  = ws + 640000;
    float* a_dst  = ws + 650000;
    int*   cnt    = (int*)(ws + 660000);
    int*   offs   = (int*)(ws + 670000);    // 10001
    int*   cursor = (int*)(ws + 680001);
    intx2* se     = (intx2*)(ws + 690002);  // +1 pad for 8B alignment

    hipMemsetAsync(cnt, 0, N_NODES * sizeof(int), stream);

    // dense_gat (625 blocks) + count rider (665 blocks), one launch
    dense_gat_count_kernel<<<DG_BLOCKS + CNT_BLOCKS, 256, 0, stream>>>(
        x, dw, db, gw, asv, adv, ei, z, a_src, a_dst, cnt);

    scan_kernel<<<1, 1024, 0, stream>>>(cnt, offs, cursor);

    const int eb = (TOTAL_EDGES + 255) / 256;
    scatter_kernel<<<eb, 256, 0, stream>>>(ei, a_src, a_dst, cursor, se);
    aggregate_kernel<<<(N_NODES * 64 + 255) / 256, 256, 0, stream>>>(
        offs, se, z, gb, emb);

    dim3 grid(79, 79);   // full grid, normal-orientation stores only
    sim_kernel<<<grid, 256, 0, stream>>>(emb, sim);
}

// Round 7
// 501.764 us; speedup vs baseline: 1.0028x; 1.0028x over previous
//
#include <hip/hip_runtime.h>
#include <math.h>

#define N_NODES 10000
#define E_EDGES 320000
#define IN_DIM 128
#define EMB 128
#define HID 64
#define NEG_SLOPE 0.2f

#define DG_BLOCKS 625          // dense_gat: 625 * 16 rows = 10000
#define CNT_BLOCKS 665         // count rider blocks
#define TOTAL_EDGES (E_EDGES + N_NODES)

typedef __attribute__((ext_vector_type(8))) short short8;     // 8 bf16 (4 VGPR)
typedef __attribute__((ext_vector_type(4))) short short4_t;   // 4 bf16
typedef __attribute__((ext_vector_type(4))) float floatx4;    // 4 fp32
typedef __attribute__((ext_vector_type(8))) float floatx8;    // 8 fp32
typedef __attribute__((ext_vector_type(2))) int   intx2;

// fp32 -> bf16 bits, round-to-nearest-even
__device__ __forceinline__ short f2bf(float f) {
    unsigned u = __float_as_uint(f);
    unsigned r = u + 0x7fffu + ((u >> 16) & 1u);
    return (short)(r >> 16);
}

__device__ __forceinline__ float sigmoidf_fast(float v) {
    return __builtin_amdgcn_rcpf(1.f + __expf(-v));
}

// ---------------------------------------------------------------------------
// Kernel A+count: blocks 0..624 run the dense+GAT GEMMs; blocks 625..1289
// count edge in-degrees (independent outputs -> count hides under the GEMMs).
// ---------------------------------------------------------------------------
__global__ __launch_bounds__(256) void dense_gat_count_kernel(
    const float* __restrict__ x, const float* __restrict__ dw,
    const float* __restrict__ db, const float* __restrict__ gw,
    const float* __restrict__ asv, const float* __restrict__ adv,
    const int* __restrict__ ei,
    float* __restrict__ z, float* __restrict__ a_src, float* __restrict__ a_dst,
    int* __restrict__ cnt)
{
    __shared__ float smem[8192];         // 32 KB
    const int t = threadIdx.x;
    const int b = blockIdx.x;

    if (b >= DG_BLOCKS) {                // ---- count rider ----
        const int nth = CNT_BLOCKS * 256;
        for (int e = (b - DG_BLOCKS) * 256 + t; e < TOTAL_EDGES; e += nth) {
            int s, d;
            if (e < E_EDGES) { s = ei[e]; d = ei[E_EDGES + e]; }
            else             { s = d = e - E_EDGES; }
            if ((unsigned)s >= N_NODES || (unsigned)d >= N_NODES) continue;
            atomicAdd(&cnt[d], 1);
        }
        return;
    }

    float* const xs  = smem;             // [16][128]
    float* const hs  = smem + 2048;      // [16][128]
    float* const wsm = smem + 4096;      // [32*128] / [64*64]
    const int row0 = b * 16;             // 10000 % 16 == 0

    #pragma unroll
    for (int r = 0; r < 2; ++r) {
        const int idx = t + r * 256;           // 0..511 float4 slots
        const int row = idx >> 5, c4 = idx & 31;
        *(floatx4*)&xs[row * 128 + c4 * 4] =
            *(const floatx4*)&x[(row0 + row) * IN_DIM + c4 * 4];
    }

    // GEMM1: col = t&127, rows (t>>7)*8 .. +8
    const int col = t & 127, rb = (t >> 7) * 8;
    float acc[8];
    {
        const float bias = db[col];
        #pragma unroll
        for (int r = 0; r < 8; ++r) acc[r] = bias;
    }
    for (int ch = 0; ch < 4; ++ch) {
        __syncthreads();                       // xs ready (ch=0) / wsm reads done
        #pragma unroll
        for (int r = 0; r < 4; ++r) {          // stage dw[ch*32..+32][0..128]
            const int idx = t + r * 256;
            const int row = idx >> 5, c4 = idx & 31;
            *(floatx4*)&wsm[row * 128 + c4 * 4] =
                *(const floatx4*)&dw[(ch * 32 + row) * EMB + c4 * 4];
        }
        __syncthreads();
        #pragma unroll
        for (int jg = 0; jg < 8; ++jg) {
            const int jb = jg * 4;
            floatx4 xr[8];
            #pragma unroll
            for (int r = 0; r < 8; ++r)
                xr[r] = *(const floatx4*)&xs[(rb + r) * 128 + ch * 32 + jb];
            float wv[4];
            #pragma unroll
            for (int k = 0; k < 4; ++k) wv[k] = wsm[(jb + k) * 128 + col];
            #pragma unroll
            for (int k = 0; k < 4; ++k)
                #pragma unroll
                for (int r = 0; r < 8; ++r) acc[r] = fmaf(xr[r][k], wv[k], acc[r]);
        }
    }
    #pragma unroll
    for (int r = 0; r < 8; ++r) hs[(rb + r) * 128 + col] = fmaxf(acc[r], 0.f);

    // GEMM2: col2 = t&63, rows (t>>6)*4 .. +4
    const int col2 = t & 63, rb2 = (t >> 6) * 4;
    float acc2[4] = {0.f, 0.f, 0.f, 0.f};
    for (int ch = 0; ch < 2; ++ch) {
        __syncthreads();                       // hs ready / wsm reads done
        #pragma unroll
        for (int r = 0; r < 4; ++r) {          // stage gw[ch*64..+64][0..64]
            const int idx = t + r * 256;
            const int row = idx >> 4, c4 = idx & 15;
            *(floatx4*)&wsm[row * 64 + c4 * 4] =
                *(const floatx4*)&gw[(ch * 64 + row) * HID + c4 * 4];
        }
        __syncthreads();
        #pragma unroll
        for (int kg = 0; kg < 16; ++kg) {
            const int kb = kg * 4;
            floatx4 hr[4];
            #pragma unroll
            for (int r = 0; r < 4; ++r)
                hr[r] = *(const floatx4*)&hs[(rb2 + r) * 128 + ch * 64 + kb];
            float gv[4];
            #pragma unroll
            for (int k = 0; k < 4; ++k) gv[k] = wsm[(kb + k) * 64 + col2];
            #pragma unroll
            for (int k = 0; k < 4; ++k)
                #pragma unroll
                for (int r = 0; r < 4; ++r) acc2[r] = fmaf(hr[r][k], gv[k], acc2[r]);
        }
    }

    // store z + fused attention dot products (wave holds full row of 64 cols)
    const float as_c = asv[col2], ad_c = adv[col2];
    #pragma unroll
    for (int r = 0; r < 4; ++r) {
        z[(row0 + rb2 + r) * HID + col2] = acc2[r];
        float ps = acc2[r] * as_c;
        float pd = acc2[r] * ad_c;
        #pragma unroll
        for (int off = 32; off > 0; off >>= 1) {
            ps += __shfl_down(ps, off, 64);
            pd += __shfl_down(pd, off, 64);
        }
        if ((t & 63) == 0) {
            a_src[row0 + rb2 + r] = ps;
            a_dst[row0 + rb2 + r] = pd;
        }
    }
}

// ---------------------------------------------------------------------------
// scan: single block, 1024 threads, 10 items each (10240 >= 10000).
// ---------------------------------------------------------------------------
__global__ __launch_bounds__(1024) void scan_kernel(
    const int* __restrict__ cnt, int* __restrict__ offs, int* __restrict__ cursor)
{
    __shared__ int part[1024];
    const int t = threadIdx.x;
    const int base = t * 10;
    int vals[10];
    int local = 0;
    #pragma unroll
    for (int i = 0; i < 10; ++i) {
        const int idx = base + i;
        const int c = (idx < N_NODES) ? cnt[idx] : 0;
        vals[i] = c;
        local += c;
    }
    part[t] = local;
    __syncthreads();
    for (int off = 1; off < 1024; off <<= 1) {  // Hillis-Steele inclusive
        const int v = (t >= off) ? part[t - off] : 0;
        __syncthreads();
        part[t] += v;
        __syncthreads();
    }
    int running = (t == 0) ? 0 : part[t - 1];   // exclusive base
    #pragma unroll
    for (int i = 0; i < 10; ++i) {
        const int idx = base + i;
        if (idx < N_NODES) { offs[idx] = running; cursor[idx] = running; }
        running += vals[i];
    }
    if (t == 1023) offs[N_NODES] = running;
}

// ---------------------------------------------------------------------------
__global__ __launch_bounds__(256) void scatter_kernel(
    const int* __restrict__ ei, const float* __restrict__ a_src,
    const float* __restrict__ a_dst, int* __restrict__ cursor,
    intx2* __restrict__ se)
{
    const int e = blockIdx.x * blockDim.x + threadIdx.x;
    if (e >= TOTAL_EDGES) return;
    int s, d;
    if (e < E_EDGES) {
        s = __builtin_nontemporal_load(&ei[e]);
        d = __builtin_nontemporal_load(&ei[E_EDGES + e]);
    } else {
        s = d = e - E_EDGES;
    }
    if ((unsigned)s >= N_NODES || (unsigned)d >= N_NODES) return;
    float v = a_src[s] + a_dst[d];
    v = (v > 0.f) ? v : NEG_SLOPE * v;
    const float w = __expf(v);          // max-shift skipped: |v| small, fp32 safe
    const int pos = atomicAdd(&cursor[d], 1);
    intx2 p;
    p[0] = s;
    p[1] = __float_as_int(w);
    se[pos] = p;                        // one 8B record (cached store)
}

// ---------------------------------------------------------------------------
// aggregate: one wave per node; 8 edge subgroups of 8 lanes x float8.
// Also emits emb16 (bf16 copy of emb) when workspace permits -- this is the
// operand table sim_fast loads fragments from directly.
// ---------------------------------------------------------------------------
__global__ __launch_bounds__(256) void aggregate_kernel(
    const int* __restrict__ offs, const intx2* __restrict__ se,
    const float* __restrict__ z, const float* __restrict__ gb,
    float* __restrict__ emb, short* __restrict__ emb16)
{
    const int wid  = (blockIdx.x * blockDim.x + threadIdx.x) >> 6;
    const int lane = threadIdx.x & 63;
    if (wid >= N_NODES) return;
    const int g  = lane >> 3;            // edge subgroup 0..7
    const int c8 = (lane & 7) * 8;       // feature slot (8 floats = 32B)
    const int beg = offs[wid], end = offs[wid + 1];
    floatx8 acc = {0.f, 0.f, 0.f, 0.f, 0.f, 0.f, 0.f, 0.f};
    float sw = 0.f;
    for (int i = beg + g; i < end; i += 8) {
        const intx2 p = __builtin_nontemporal_load(&se[i]);   // broadcast in group
        const floatx8 zv = *(const floatx8*)&z[p[0] * HID + c8];
        const float w = __int_as_float(p[1]);
        acc += zv * w;
        sw  += w;
    }
    #pragma unroll
    for (int off = 8; off <= 32; off <<= 1) {
        #pragma unroll
        for (int k = 0; k < 8; ++k) acc[k] += __shfl_xor(acc[k], off, 64);
        sw += __shfl_xor(sw, off, 64);
    }
    if (g == 0) {                        // lanes 0..7 cover the 64-col row
        const floatx8 gv = *(const floatx8*)&gb[c8];
        floatx8 r;
        #pragma unroll
        for (int k = 0; k < 8; ++k) r[k] = acc[k] / sw + gv[k];
        __builtin_nontemporal_store(r, (floatx8*)&emb[wid * HID + c8]);
        if (emb16) {
            short8 rb;
            #pragma unroll
            for (int k = 0; k < 8; ++k) rb[k] = f2bf(r[k]);
            *(short8*)&emb16[wid * HID + c8] = rb;
        }
    }
}

// ---------------------------------------------------------------------------
// sim_fast: sim = sigmoid(emb @ emb^T) with fragments loaded DIRECTLY from
// the precomputed bf16 table emb16 (1.28 MB, L2-resident). The MFMA operand
// layout (8 consecutive k for one node) is 16 contiguous bytes of a row, so
// A and B frags are plain 16B global loads (2KB contiguous per wave-load).
// No staging, no per-tile f2bf, no A/B LDS, one fewer barrier. Epilogue
// unchanged: sigmoid half-tile into [64][133] f32 scratch, 512B NT runs.
// LDS = 34048 B -> 4 blocks/CU. Bit-identical math to the staging variant.
// ---------------------------------------------------------------------------
#define SCR 133
__global__ __launch_bounds__(256, 4) void sim_fast_kernel(
    const short* __restrict__ emb16, float* __restrict__ sim)
{
    __shared__ float scr[64 * SCR];          // 34048 B
    const int t    = threadIdx.x;
    const int lane = t & 63;
    const int wave = t >> 6;                 // 0..3
    const int l15  = lane & 15;
    const int quad = lane >> 4;              // 0..3

    const int bi = blockIdx.y;               // row tile
    const int bj = blockIdx.x;               // col tile

    // ---- A fragments: rows (ti*4+wave)*16 + l15 (interleaved ownership) ----
    short8 afrag[2][2];
    #pragma unroll
    for (int ti = 0; ti < 2; ++ti) {
        int gr = bi * 128 + (ti * 4 + wave) * 16 + l15;
        if (gr > N_NODES - 1) gr = N_NODES - 1;
        #pragma unroll
        for (int ks = 0; ks < 2; ++ks)
            afrag[ti][ks] = *(const short8*)&emb16[gr * HID + ks * 32 + quad * 8];
    }

    floatx4 acc[2][8];
    const floatx4 zero = {0.f, 0.f, 0.f, 0.f};
    #pragma unroll
    for (int ti = 0; ti < 2; ++ti)
        #pragma unroll
        for (int tj = 0; tj < 8; ++tj) acc[ti][tj] = zero;

    #pragma unroll
    for (int tj = 0; tj < 8; ++tj) {
        int gc = bj * 128 + tj * 16 + l15;
        if (gc > N_NODES - 1) gc = N_NODES - 1;
        const short8 bf0 = *(const short8*)&emb16[gc * HID + quad * 8];
        const short8 bf1 = *(const short8*)&emb16[gc * HID + 32 + quad * 8];
        #pragma unroll
        for (int ti = 0; ti < 2; ++ti) {
            acc[ti][tj] = __builtin_amdgcn_mfma_f32_16x16x32_bf16(
                afrag[ti][0], bf0, acc[ti][tj], 0, 0, 0);
            acc[ti][tj] = __builtin_amdgcn_mfma_f32_16x16x32_bf16(
                afrag[ti][1], bf1, acc[ti][tj], 0, 0, 0);
        }
    }

    // ---- epilogue: two 64-row halves; every wave active in each phase ----
    #pragma unroll
    for (int h = 0; h < 2; ++h) {
        // wave's fragment ti=h covers rows-in-half wave*16 .. +16
        // C/D layout: row = quad*4+reg (within 16), col = l15
        #pragma unroll
        for (int reg = 0; reg < 4; ++reg)
            #pragma unroll
            for (int tj = 0; tj < 8; ++tj)
                scr[(wave * 16 + quad * 4 + reg) * SCR + tj * 16 + l15] =
                    sigmoidf_fast(acc[h][tj][reg]);
        __syncthreads();

        // 64 rows x 128 cols, 512B contiguous NT float4 runs
        #pragma unroll
        for (int round = 0; round < 8; ++round) {
            const int idx = t + round * 256;         // 0..2047
            const int rr = idx >> 5, cq = idx & 31;
            const int grow = bi * 128 + (h * 4 + (rr >> 4)) * 16 + (rr & 15);
            const int gcol = bj * 128 + cq * 4;
            if (grow < N_NODES && gcol < N_NODES) {
                const floatx4 v4 = *(const floatx4*)&scr[rr * SCR + cq * 4];
                __builtin_nontemporal_store(
                    v4, (floatx4*)&sim[(unsigned)grow * N_NODES + gcol]);
            }
        }
        __syncthreads();    // scratch reads done before next half overwrites
    }
}

// ---------------------------------------------------------------------------
// Fallback sim (R6 staging variant) -- used only if workspace lacks emb16.
// ---------------------------------------------------------------------------
#define SROW 72
__global__ __launch_bounds__(256, 4) void sim_kernel(
    const float* __restrict__ emb, float* __restrict__ sim)
{
    __shared__ float smem[9216];                   // 36864 B
    short* const As = (short*)smem;                // [128*72] bf16
    short* const Bs = (short*)smem + 128 * SROW;   // [128*72] bf16
    float* const scr = smem;                       // [64][133] f32 (aliased)
    const int t    = threadIdx.x;
    const int lane = t & 63;
    const int wave = t >> 6;
    const int l15  = lane & 15;
    const int quad = lane >> 4;

    const int bi = blockIdx.y;
    const int bj = blockIdx.x;

    #pragma unroll
    for (int round = 0; round < 8; ++round) {
        const int idx = t + round * 256;
        const int row = idx >> 4, c4 = idx & 15;
        int gr = bi * 128 + row; if (gr > N_NODES - 1) gr = N_NODES - 1;
        int gc = bj * 128 + row; if (gc > N_NODES - 1) gc = N_NODES - 1;
        const floatx4 a = *(const floatx4*)&emb[gr * HID + c4 * 4];
        const floatx4 b = *(const floatx4*)&emb[gc * HID + c4 * 4];
        short4_t sa, sb;
        #pragma unroll
        for (int j = 0; j < 4; ++j) { sa[j] = f2bf(a[j]); sb[j] = f2bf(b[j]); }
        *(short4_t*)&As[row * SROW + c4 * 4] = sa;
        *(short4_t*)&Bs[row * SROW + c4 * 4] = sb;
    }
    __syncthreads();

    short8 afrag[2][2];
    #pragma unroll
    for (int ti = 0; ti < 2; ++ti)
        #pragma unroll
        for (int ks = 0; ks < 2; ++ks)
            afrag[ti][ks] = *(const short8*)&As[((ti * 4 + wave) * 16 + l15) * SROW +
                                                ks * 32 + quad * 8];

    floatx4 acc[2][8];
    const floatx4 zero = {0.f, 0.f, 0.f, 0.f};
    #pragma unroll
    for (int ti = 0; ti < 2; ++ti)
        #pragma unroll
        for (int tj = 0; tj < 8; ++tj) acc[ti][tj] = zero;

    #pragma unroll
    for (int tj = 0; tj < 8; ++tj) {
        const short8 bf0 = *(const short8*)&Bs[(tj * 16 + l15) * SROW + quad * 8];
        const short8 bf1 = *(const short8*)&Bs[(tj * 16 + l15) * SROW + 32 + quad * 8];
        #pragma unroll
        for (int ti = 0; ti < 2; ++ti) {
            acc[ti][tj] = __builtin_amdgcn_mfma_f32_16x16x32_bf16(
                afrag[ti][0], bf0, acc[ti][tj], 0, 0, 0);
            acc[ti][tj] = __builtin_amdgcn_mfma_f32_16x16x32_bf16(
                afrag[ti][1], bf1, acc[ti][tj], 0, 0, 0);
        }
    }
    __syncthreads();

    #pragma unroll
    for (int h = 0; h < 2; ++h) {
        #pragma unroll
        for (int reg = 0; reg < 4; ++reg)
            #pragma unroll
            for (int tj = 0; tj < 8; ++tj)
                scr[(wave * 16 + quad * 4 + reg) * SCR + tj * 16 + l15] =
                    sigmoidf_fast(acc[h][tj][reg]);
        __syncthreads();

        #pragma unroll
        for (int round = 0; round < 8; ++round) {
            const int idx = t + round * 256;
            const int rr = idx >> 5, cq = idx & 31;
            const int grow = bi * 128 + (h * 4 + (rr >> 4)) * 16 + (rr & 15);
            const int gcol = bj * 128 + cq * 4;
            if (grow < N_NODES && gcol < N_NODES) {
                const floatx4 v4 = *(const floatx4*)&scr[rr * SCR + cq * 4];
                __builtin_nontemporal_store(
                    v4, (floatx4*)&sim[(unsigned)grow * N_NODES + gcol]);
            }
        }
        __syncthreads();
    }
}

// ---------------------------------------------------------------------------
extern "C" void kernel_launch(void* const* d_in, const int* in_sizes, int n_in,
                              void* d_out, int out_size, void* d_ws, size_t ws_size,
                              hipStream_t stream)
{
    const float* x   = (const float*)d_in[0];
    const int*   ei  = (const int*)d_in[1];   // edge_index int32 [2,E]
    const float* dw  = (const float*)d_in[2];
    const float* db  = (const float*)d_in[3];
    const float* gw  = (const float*)d_in[4];
    const float* asv = (const float*)d_in[5];
    const float* adv = (const float*)d_in[6];
    const float* gb  = (const float*)d_in[7];

    float* out = (float*)d_out;
    float* sim = out;                                   // [N*N]
    float* emb = out + (size_t)N_NODES * N_NODES;       // [N*HID]

    // Scratch layout (floats):
    // z 640000 | a_src 10000 | a_dst 10000 | cnt 10000 | offs 10001 |
    // cursor 10000 | pad 1 | se (int2) 660000 | pad 2 | emb16 (bf16) 320000
    const size_t need_base  = 1350002u * sizeof(float);
    const size_t need_emb16 = 1670004u * sizeof(float);
    float* ws = (ws_size >= need_base) ? (float*)d_ws : out;
    float* z      = ws;
    float* a_src  = ws + 640000;
    float* a_dst  = ws + 650000;
    int*   cnt    = (int*)(ws + 660000);
    int*   offs   = (int*)(ws + 670000);    // 10001
    int*   cursor = (int*)(ws + 680001);
    intx2* se     = (intx2*)(ws + 690002);  // +1 pad for 8B alignment
    const bool has16 = (ws_size >= need_emb16);
    short* emb16  = has16 ? (short*)(ws + 1350004) : nullptr;  // 16B aligned

    hipMemsetAsync(cnt, 0, N_NODES * sizeof(int), stream);

    // dense_gat (625 blocks) + count rider (665 blocks), one launch
    dense_gat_count_kernel<<<DG_BLOCKS + CNT_BLOCKS, 256, 0, stream>>>(
        x, dw, db, gw, asv, adv, ei, z, a_src, a_dst, cnt);

    scan_kernel<<<1, 1024, 0, stream>>>(cnt, offs, cursor);

    const int eb = (TOTAL_EDGES + 255) / 256;
    scatter_kernel<<<eb, 256, 0, stream>>>(ei, a_src, a_dst, cursor, se);
    aggregate_kernel<<<(N_NODES * 64 + 255) / 256, 256, 0, stream>>>(
        offs, se, z, gb, emb, emb16);

    dim3 grid(79, 79);
    if (has16) sim_fast_kernel<<<grid, 256, 0, stream>>>(emb16, sim);
    else       sim_kernel<<<grid, 256, 0, stream>>>(emb, sim);
}

// Round 8
// 498.670 us; speedup vs baseline: 1.0090x; 1.0062x over previous
//
#include <hip/hip_runtime.h>
#include <math.h>

#define N_NODES 10000
#define E_EDGES 320000
#define IN_DIM 128
#define EMB 128
#define HID 64
#define NEG_SLOPE 0.2f

#define DG_BLOCKS 625          // dense_gat: 625 * 16 rows = 10000
#define CNT_BLOCKS 665         // count rider blocks
#define TOTAL_EDGES (E_EDGES + N_NODES)

typedef __attribute__((ext_vector_type(8))) short short8;     // 8 bf16 (4 VGPR)
typedef __attribute__((ext_vector_type(4))) short short4_t;   // 4 bf16
typedef __attribute__((ext_vector_type(4))) float floatx4;    // 4 fp32
typedef __attribute__((ext_vector_type(8))) float floatx8;    // 8 fp32
typedef __attribute__((ext_vector_type(2))) int   intx2;

// fp32 -> bf16 bits, round-to-nearest-even
__device__ __forceinline__ short f2bf(float f) {
    unsigned u = __float_as_uint(f);
    unsigned r = u + 0x7fffu + ((u >> 16) & 1u);
    return (short)(r >> 16);
}

__device__ __forceinline__ float sigmoidf_fast(float v) {
    return __builtin_amdgcn_rcpf(1.f + __expf(-v));
}

// ---------------------------------------------------------------------------
// Kernel A+count: blocks 0..624 run the dense+GAT GEMMs; blocks 625..1289
// count edge in-degrees (independent outputs -> count hides under the GEMMs).
// ---------------------------------------------------------------------------
__global__ __launch_bounds__(256) void dense_gat_count_kernel(
    const float* __restrict__ x, const float* __restrict__ dw,
    const float* __restrict__ db, const float* __restrict__ gw,
    const float* __restrict__ asv, const float* __restrict__ adv,
    const int* __restrict__ ei,
    float* __restrict__ z, float* __restrict__ a_src, float* __restrict__ a_dst,
    int* __restrict__ cnt)
{
    __shared__ float smem[8192];         // 32 KB
    const int t = threadIdx.x;
    const int b = blockIdx.x;

    if (b >= DG_BLOCKS) {                // ---- count rider ----
        const int nth = CNT_BLOCKS * 256;
        for (int e = (b - DG_BLOCKS) * 256 + t; e < TOTAL_EDGES; e += nth) {
            int s, d;
            if (e < E_EDGES) { s = ei[e]; d = ei[E_EDGES + e]; }
            else             { s = d = e - E_EDGES; }
            if ((unsigned)s >= N_NODES || (unsigned)d >= N_NODES) continue;
            atomicAdd(&cnt[d], 1);
        }
        return;
    }

    float* const xs  = smem;             // [16][128]
    float* const hs  = smem + 2048;      // [16][128]
    float* const wsm = smem + 4096;      // [32*128] / [64*64]
    const int row0 = b * 16;             // 10000 % 16 == 0

    #pragma unroll
    for (int r = 0; r < 2; ++r) {
        const int idx = t + r * 256;           // 0..511 float4 slots
        const int row = idx >> 5, c4 = idx & 31;
        *(floatx4*)&xs[row * 128 + c4 * 4] =
            *(const floatx4*)&x[(row0 + row) * IN_DIM + c4 * 4];
    }

    // GEMM1: col = t&127, rows (t>>7)*8 .. +8
    const int col = t & 127, rb = (t >> 7) * 8;
    float acc[8];
    {
        const float bias = db[col];
        #pragma unroll
        for (int r = 0; r < 8; ++r) acc[r] = bias;
    }
    for (int ch = 0; ch < 4; ++ch) {
        __syncthreads();                       // xs ready (ch=0) / wsm reads done
        #pragma unroll
        for (int r = 0; r < 4; ++r) {          // stage dw[ch*32..+32][0..128]
            const int idx = t + r * 256;
            const int row = idx >> 5, c4 = idx & 31;
            *(floatx4*)&wsm[row * 128 + c4 * 4] =
                *(const floatx4*)&dw[(ch * 32 + row) * EMB + c4 * 4];
        }
        __syncthreads();
        #pragma unroll
        for (int jg = 0; jg < 8; ++jg) {
            const int jb = jg * 4;
            floatx4 xr[8];
            #pragma unroll
            for (int r = 0; r < 8; ++r)
                xr[r] = *(const floatx4*)&xs[(rb + r) * 128 + ch * 32 + jb];
            float wv[4];
            #pragma unroll
            for (int k = 0; k < 4; ++k) wv[k] = wsm[(jb + k) * 128 + col];
            #pragma unroll
            for (int k = 0; k < 4; ++k)
                #pragma unroll
                for (int r = 0; r < 8; ++r) acc[r] = fmaf(xr[r][k], wv[k], acc[r]);
        }
    }
    #pragma unroll
    for (int r = 0; r < 8; ++r) hs[(rb + r) * 128 + col] = fmaxf(acc[r], 0.f);

    // GEMM2: col2 = t&63, rows (t>>6)*4 .. +4
    const int col2 = t & 63, rb2 = (t >> 6) * 4;
    float acc2[4] = {0.f, 0.f, 0.f, 0.f};
    for (int ch = 0; ch < 2; ++ch) {
        __syncthreads();                       // hs ready / wsm reads done
        #pragma unroll
        for (int r = 0; r < 4; ++r) {          // stage gw[ch*64..+64][0..64]
            const int idx = t + r * 256;
            const int row = idx >> 4, c4 = idx & 15;
            *(floatx4*)&wsm[row * 64 + c4 * 4] =
                *(const floatx4*)&gw[(ch * 64 + row) * HID + c4 * 4];
        }
        __syncthreads();
        #pragma unroll
        for (int kg = 0; kg < 16; ++kg) {
            const int kb = kg * 4;
            floatx4 hr[4];
            #pragma unroll
            for (int r = 0; r < 4; ++r)
                hr[r] = *(const floatx4*)&hs[(rb2 + r) * 128 + ch * 64 + kb];
            float gv[4];
            #pragma unroll
            for (int k = 0; k < 4; ++k) gv[k] = wsm[(kb + k) * 64 + col2];
            #pragma unroll
            for (int k = 0; k < 4; ++k)
                #pragma unroll
                for (int r = 0; r < 4; ++r) acc2[r] = fmaf(hr[r][k], gv[k], acc2[r]);
        }
    }

    // store z + fused attention dot products (wave holds full row of 64 cols)
    const float as_c = asv[col2], ad_c = adv[col2];
    #pragma unroll
    for (int r = 0; r < 4; ++r) {
        z[(row0 + rb2 + r) * HID + col2] = acc2[r];
        float ps = acc2[r] * as_c;
        float pd = acc2[r] * ad_c;
        #pragma unroll
        for (int off = 32; off > 0; off >>= 1) {
            ps += __shfl_down(ps, off, 64);
            pd += __shfl_down(pd, off, 64);
        }
        if ((t & 63) == 0) {
            a_src[row0 + rb2 + r] = ps;
            a_dst[row0 + rb2 + r] = pd;
        }
    }
}

// ---------------------------------------------------------------------------
// scan: single block, 1024 threads, 10 items each (10240 >= 10000).
// ---------------------------------------------------------------------------
__global__ __launch_bounds__(1024) void scan_kernel(
    const int* __restrict__ cnt, int* __restrict__ offs, int* __restrict__ cursor)
{
    __shared__ int part[1024];
    const int t = threadIdx.x;
    const int base = t * 10;
    int vals[10];
    int local = 0;
    #pragma unroll
    for (int i = 0; i < 10; ++i) {
        const int idx = base + i;
        const int c = (idx < N_NODES) ? cnt[idx] : 0;
        vals[i] = c;
        local += c;
    }
    part[t] = local;
    __syncthreads();
    for (int off = 1; off < 1024; off <<= 1) {  // Hillis-Steele inclusive
        const int v = (t >= off) ? part[t - off] : 0;
        __syncthreads();
        part[t] += v;
        __syncthreads();
    }
    int running = (t == 0) ? 0 : part[t - 1];   // exclusive base
    #pragma unroll
    for (int i = 0; i < 10; ++i) {
        const int idx = base + i;
        if (idx < N_NODES) { offs[idx] = running; cursor[idx] = running; }
        running += vals[i];
    }
    if (t == 1023) offs[N_NODES] = running;
}

// ---------------------------------------------------------------------------
__global__ __launch_bounds__(256) void scatter_kernel(
    const int* __restrict__ ei, const float* __restrict__ a_src,
    const float* __restrict__ a_dst, int* __restrict__ cursor,
    intx2* __restrict__ se)
{
    const int e = blockIdx.x * blockDim.x + threadIdx.x;
    if (e >= TOTAL_EDGES) return;
    int s, d;
    if (e < E_EDGES) {
        s = __builtin_nontemporal_load(&ei[e]);
        d = __builtin_nontemporal_load(&ei[E_EDGES + e]);
    } else {
        s = d = e - E_EDGES;
    }
    if ((unsigned)s >= N_NODES || (unsigned)d >= N_NODES) return;
    float v = a_src[s] + a_dst[d];
    v = (v > 0.f) ? v : NEG_SLOPE * v;
    const float w = __expf(v);          // max-shift skipped: |v| small, fp32 safe
    const int pos = atomicAdd(&cursor[d], 1);
    intx2 p;
    p[0] = s;
    p[1] = __float_as_int(w);
    se[pos] = p;                        // one 8B record (cached store)
}

// ---------------------------------------------------------------------------
// aggregate: one wave per node; 8 edge subgroups of 8 lanes x float8.
// Also emits emb16 (bf16 copy of emb) when workspace permits.
// ---------------------------------------------------------------------------
__global__ __launch_bounds__(256) void aggregate_kernel(
    const int* __restrict__ offs, const intx2* __restrict__ se,
    const float* __restrict__ z, const float* __restrict__ gb,
    float* __restrict__ emb, short* __restrict__ emb16)
{
    const int wid  = (blockIdx.x * blockDim.x + threadIdx.x) >> 6;
    const int lane = threadIdx.x & 63;
    if (wid >= N_NODES) return;
    const int g  = lane >> 3;            // edge subgroup 0..7
    const int c8 = (lane & 7) * 8;       // feature slot (8 floats = 32B)
    const int beg = offs[wid], end = offs[wid + 1];
    floatx8 acc = {0.f, 0.f, 0.f, 0.f, 0.f, 0.f, 0.f, 0.f};
    float sw = 0.f;
    for (int i = beg + g; i < end; i += 8) {
        const intx2 p = __builtin_nontemporal_load(&se[i]);   // broadcast in group
        const floatx8 zv = *(const floatx8*)&z[p[0] * HID + c8];
        const float w = __int_as_float(p[1]);
        acc += zv * w;
        sw  += w;
    }
    #pragma unroll
    for (int off = 8; off <= 32; off <<= 1) {
        #pragma unroll
        for (int k = 0; k < 8; ++k) acc[k] += __shfl_xor(acc[k], off, 64);
        sw += __shfl_xor(sw, off, 64);
    }
    if (g == 0) {                        // lanes 0..7 cover the 64-col row
        const floatx8 gv = *(const floatx8*)&gb[c8];
        floatx8 r;
        #pragma unroll
        for (int k = 0; k < 8; ++k) r[k] = acc[k] / sw + gv[k];
        __builtin_nontemporal_store(r, (floatx8*)&emb[wid * HID + c8]);
        if (emb16) {
            short8 rb;
            #pragma unroll
            for (int k = 0; k < 8; ++k) rb[k] = f2bf(r[k]);
            *(short8*)&emb16[wid * HID + c8] = rb;
        }
    }
}

// ---------------------------------------------------------------------------
// sim_fast v2: 32x512 tiles. Fragments direct from the bf16 table emb16
// (L2-resident). Per-row store runs are 2 KB contiguous (was 512 B) and each
// wave-level store instruction covers 1 KB contiguous -> 4x fewer DRAM page
// activations in the 400 MB NT store stream. Per-wave: 128-col strip, 2 row
// frags x 8 col frags (64 acc VGPR). Epilogue: two 16-row halves through a
// [16][516] f32 scratch (33 KB -> 4 blocks/CU). Same MFMA K-order and
// sigmoid as before -> bit-identical output.
// ---------------------------------------------------------------------------
#define SCRW 516
__global__ __launch_bounds__(256, 4) void sim_fast_kernel(
    const short* __restrict__ emb16, float* __restrict__ sim)
{
    __shared__ float scr[16 * SCRW];         // 33024 B
    const int t    = threadIdx.x;
    const int lane = t & 63;
    const int wave = t >> 6;                 // 0..3
    const int l15  = lane & 15;
    const int quad = lane >> 4;              // 0..3

    const int bi = blockIdx.y;               // row tile (32 rows)
    const int bj = blockIdx.x;               // col tile (512 cols)

    // ---- A fragments: rows bi*32 + ri*16 + l15 ----
    short8 afrag[2][2];
    #pragma unroll
    for (int ri = 0; ri < 2; ++ri) {
        int gr = bi * 32 + ri * 16 + l15;
        if (gr > N_NODES - 1) gr = N_NODES - 1;
        #pragma unroll
        for (int ks = 0; ks < 2; ++ks)
            afrag[ri][ks] = *(const short8*)&emb16[gr * HID + ks * 32 + quad * 8];
    }

    floatx4 acc[2][8];
    const floatx4 zero = {0.f, 0.f, 0.f, 0.f};
    #pragma unroll
    for (int ri = 0; ri < 2; ++ri)
        #pragma unroll
        for (int tj = 0; tj < 8; ++tj) acc[ri][tj] = zero;

    // ---- B fragments: wave owns cols bj*512 + wave*128 + tj*16 + l15 ----
    #pragma unroll
    for (int tj = 0; tj < 8; ++tj) {
        int gc = bj * 512 + wave * 128 + tj * 16 + l15;
        if (gc > N_NODES - 1) gc = N_NODES - 1;
        const short8 bf0 = *(const short8*)&emb16[gc * HID + quad * 8];
        const short8 bf1 = *(const short8*)&emb16[gc * HID + 32 + quad * 8];
        #pragma unroll
        for (int ri = 0; ri < 2; ++ri) {
            acc[ri][tj] = __builtin_amdgcn_mfma_f32_16x16x32_bf16(
                afrag[ri][0], bf0, acc[ri][tj], 0, 0, 0);
            acc[ri][tj] = __builtin_amdgcn_mfma_f32_16x16x32_bf16(
                afrag[ri][1], bf1, acc[ri][tj], 0, 0, 0);
        }
    }

    // ---- epilogue: two 16-row halves; every wave active in each phase ----
    #pragma unroll
    for (int h = 0; h < 2; ++h) {
        // C/D layout: row-in-frag = quad*4+reg, col = l15
        #pragma unroll
        for (int reg = 0; reg < 4; ++reg)
            #pragma unroll
            for (int tj = 0; tj < 8; ++tj)
                scr[(quad * 4 + reg) * SCRW + wave * 128 + tj * 16 + l15] =
                    sigmoidf_fast(acc[h][tj][reg]);
        __syncthreads();

        // 16 rows x 512 cols: per-row 2 KB runs, per-wave 1 KB contiguous
        #pragma unroll
        for (int round = 0; round < 8; ++round) {
            const int idx = t + round * 256;         // 0..2047
            const int rr = idx >> 7, cq = idx & 127;
            const int grow = bi * 32 + h * 16 + rr;
            const int gcol = bj * 512 + cq * 4;      // N%4==0 -> no partial vec
            if (grow < N_NODES && gcol < N_NODES) {
                const floatx4 v4 = *(const floatx4*)&scr[rr * SCRW + cq * 4];
                __builtin_nontemporal_store(
                    v4, (floatx4*)&sim[(unsigned)grow * N_NODES + gcol]);
            }
        }
        __syncthreads();    // scratch reads done before next half overwrites
    }
}

// ---------------------------------------------------------------------------
// Fallback sim (staging variant, 128x128, grid 79x79) -- used only if the
// workspace lacks room for emb16.
// ---------------------------------------------------------------------------
#define SROW 72
#define SCR 133
__global__ __launch_bounds__(256, 4) void sim_kernel(
    const float* __restrict__ emb, float* __restrict__ sim)
{
    __shared__ float smem[9216];                   // 36864 B
    short* const As = (short*)smem;                // [128*72] bf16
    short* const Bs = (short*)smem + 128 * SROW;   // [128*72] bf16
    float* const scr = smem;                       // [64][133] f32 (aliased)
    const int t    = threadIdx.x;
    const int lane = t & 63;
    const int wave = t >> 6;
    const int l15  = lane & 15;
    const int quad = lane >> 4;

    const int bi = blockIdx.y;
    const int bj = blockIdx.x;

    #pragma unroll
    for (int round = 0; round < 8; ++round) {
        const int idx = t + round * 256;
        const int row = idx >> 4, c4 = idx & 15;
        int gr = bi * 128 + row; if (gr > N_NODES - 1) gr = N_NODES - 1;
        int gc = bj * 128 + row; if (gc > N_NODES - 1) gc = N_NODES - 1;
        const floatx4 a = *(const floatx4*)&emb[gr * HID + c4 * 4];
        const floatx4 b = *(const floatx4*)&emb[gc * HID + c4 * 4];
        short4_t sa, sb;
        #pragma unroll
        for (int j = 0; j < 4; ++j) { sa[j] = f2bf(a[j]); sb[j] = f2bf(b[j]); }
        *(short4_t*)&As[row * SROW + c4 * 4] = sa;
        *(short4_t*)&Bs[row * SROW + c4 * 4] = sb;
    }
    __syncthreads();

    short8 afrag[2][2];
    #pragma unroll
    for (int ti = 0; ti < 2; ++ti)
        #pragma unroll
        for (int ks = 0; ks < 2; ++ks)
            afrag[ti][ks] = *(const short8*)&As[((ti * 4 + wave) * 16 + l15) * SROW +
                                                ks * 32 + quad * 8];

    floatx4 acc[2][8];
    const floatx4 zero = {0.f, 0.f, 0.f, 0.f};
    #pragma unroll
    for (int ti = 0; ti < 2; ++ti)
        #pragma unroll
        for (int tj = 0; tj < 8; ++tj) acc[ti][tj] = zero;

    #pragma unroll
    for (int tj = 0; tj < 8; ++tj) {
        const short8 bf0 = *(const short8*)&Bs[(tj * 16 + l15) * SROW + quad * 8];
        const short8 bf1 = *(const short8*)&Bs[(tj * 16 + l15) * SROW + 32 + quad * 8];
        #pragma unroll
        for (int ti = 0; ti < 2; ++ti) {
            acc[ti][tj] = __builtin_amdgcn_mfma_f32_16x16x32_bf16(
                afrag[ti][0], bf0, acc[ti][tj], 0, 0, 0);
            acc[ti][tj] = __builtin_amdgcn_mfma_f32_16x16x32_bf16(
                afrag[ti][1], bf1, acc[ti][tj], 0, 0, 0);
        }
    }
    __syncthreads();

    #pragma unroll
    for (int h = 0; h < 2; ++h) {
        #pragma unroll
        for (int reg = 0; reg < 4; ++reg)
            #pragma unroll
            for (int tj = 0; tj < 8; ++tj)
                scr[(wave * 16 + quad * 4 + reg) * SCR + tj * 16 + l15] =
                    sigmoidf_fast(acc[h][tj][reg]);
        __syncthreads();

        #pragma unroll
        for (int round = 0; round < 8; ++round) {
            const int idx = t + round * 256;
            const int rr = idx >> 5, cq = idx & 31;
            const int grow = bi * 128 + (h * 4 + (rr >> 4)) * 16 + (rr & 15);
            const int gcol = bj * 128 + cq * 4;
            if (grow < N_NODES && gcol < N_NODES) {
                const floatx4 v4 = *(const floatx4*)&scr[rr * SCR + cq * 4];
                __builtin_nontemporal_store(
                    v4, (floatx4*)&sim[(unsigned)grow * N_NODES + gcol]);
            }
        }
        __syncthreads();
    }
}

// ---------------------------------------------------------------------------
extern "C" void kernel_launch(void* const* d_in, const int* in_sizes, int n_in,
                              void* d_out, int out_size, void* d_ws, size_t ws_size,
                              hipStream_t stream)
{
    const float* x   = (const float*)d_in[0];
    const int*   ei  = (const int*)d_in[1];   // edge_index int32 [2,E]
    const float* dw  = (const float*)d_in[2];
    const float* db  = (const float*)d_in[3];
    const float* gw  = (const float*)d_in[4];
    const float* asv = (const float*)d_in[5];
    const float* adv = (const float*)d_in[6];
    const float* gb  = (const float*)d_in[7];

    float* out = (float*)d_out;
    float* sim = out;                                   // [N*N]
    float* emb = out + (size_t)N_NODES * N_NODES;       // [N*HID]

    // Scratch layout (floats):
    // z 640000 | a_src 10000 | a_dst 10000 | cnt 10000 | offs 10001 |
    // cursor 10000 | pad 1 | se (int2) 660000 | pad 2 | emb16 (bf16) 320000
    const size_t need_base  = 1350002u * sizeof(float);
    const size_t need_emb16 = 1670004u * sizeof(float);
    float* ws = (ws_size >= need_base) ? (float*)d_ws : out;
    float* z      = ws;
    float* a_src  = ws + 640000;
    float* a_dst  = ws + 650000;
    int*   cnt    = (int*)(ws + 660000);
    int*   offs   = (int*)(ws + 670000);    // 10001
    int*   cursor = (int*)(ws + 680001);
    intx2* se     = (intx2*)(ws + 690002);  // +1 pad for 8B alignment
    const bool has16 = (ws_size >= need_emb16);
    short* emb16  = has16 ? (short*)(ws + 1350004) : nullptr;  // 16B aligned

    hipMemsetAsync(cnt, 0, N_NODES * sizeof(int), stream);

    // dense_gat (625 blocks) + count rider (665 blocks), one launch
    dense_gat_count_kernel<<<DG_BLOCKS + CNT_BLOCKS, 256, 0, stream>>>(
        x, dw, db, gw, asv, adv, ei, z, a_src, a_dst, cnt);

    scan_kernel<<<1, 1024, 0, stream>>>(cnt, offs, cursor);

    const int eb = (TOTAL_EDGES + 255) / 256;
    scatter_kernel<<<eb, 256, 0, stream>>>(ei, a_src, a_dst, cursor, se);
    aggregate_kernel<<<(N_NODES * 64 + 255) / 256, 256, 0, stream>>>(
        offs, se, z, gb, emb, emb16);

    if (has16) {
        dim3 grid((N_NODES + 511) / 512, (N_NODES + 31) / 32);   // 20 x 313
        sim_fast_kernel<<<grid, 256, 0, stream>>>(emb16, sim);
    } else {
        dim3 grid(79, 79);
        sim_kernel<<<grid, 256, 0, stream>>>(emb, sim);
    }
}